// Round 5
// baseline (518.182 us; speedup 1.0000x reference)
//
#include <hip/hip_runtime.h>

// Problem shape (fixed by the reference's setup_inputs)
#define BT   16
#define NR   4096
#define FIN  1024
#define FOUT 1024

#define NCHUNK 32                    // row-chunks per batch for partial colsum
#define ROWS_PER_CHUNK (NR / NCHUNK) // 128
#define ROWS_PER_BLOCK 32            // broadcast rows per block

// Kernel 1: partial column sums of X.  grid = (NCHUNK, BT), block = 256.
// Each thread owns 4 columns (float4); sums ROWS_PER_CHUNK rows.
__global__ void colsum_partial(const float* __restrict__ X, float* __restrict__ part) {
    const int rc = blockIdx.x;
    const int b  = blockIdx.y;
    const int t  = threadIdx.x;
    const float4* src = reinterpret_cast<const float4*>(
        X + (size_t)b * NR * FIN + (size_t)rc * ROWS_PER_CHUNK * FIN) + t;
    float4 acc = {0.f, 0.f, 0.f, 0.f};
#pragma unroll 8
    for (int r = 0; r < ROWS_PER_CHUNK; ++r) {
        float4 v = src[(size_t)r * (FIN / 4)];
        acc.x += v.x; acc.y += v.y; acc.z += v.z; acc.w += v.w;
    }
    reinterpret_cast<float4*>(part + ((size_t)b * NCHUNK + rc) * FIN)[t] = acc;
}

// Kernel 2: reduce partials -> mean.  grid = BT, block = 256.
__global__ void colsum_finish(const float* __restrict__ part, float* __restrict__ mean) {
    const int b = blockIdx.x;
    const int t = threadIdx.x;
    const float4* src = reinterpret_cast<const float4*>(part + (size_t)b * NCHUNK * FIN) + t;
    float4 acc = {0.f, 0.f, 0.f, 0.f};
#pragma unroll
    for (int c = 0; c < NCHUNK; ++c) {
        float4 v = src[(size_t)c * (FIN / 4)];
        acc.x += v.x; acc.y += v.y; acc.z += v.z; acc.w += v.w;
    }
    const float inv = 1.0f / (float)NR;
    acc.x *= inv; acc.y *= inv; acc.z *= inv; acc.w *= inv;
    reinterpret_cast<float4*>(mean + (size_t)b * FIN)[t] = acc;
}

// Kernel 3: row[b] = mean[b] @ B + cT.  grid = (FOUT/256, BT), block = 256.
// mean[b] staged in LDS (all-lane broadcast reads are conflict-free);
// B reads are coalesced across fo and L2/L3-resident (4 MB unique).
__global__ void matvec_row(const float* __restrict__ mean, const float* __restrict__ Bm,
                           const float* __restrict__ cT, float* __restrict__ row) {
    const int foc = blockIdx.x;
    const int b   = blockIdx.y;
    const int t   = threadIdx.x;
    const int fo  = foc * 256 + t;
    __shared__ float sm[FIN];
    for (int i = t; i < FIN; i += 256) sm[i] = mean[(size_t)b * FIN + i];
    __syncthreads();
    float acc = cT[fo];
#pragma unroll 8
    for (int fi = 0; fi < FIN; ++fi) {
        acc += sm[fi] * Bm[(size_t)fi * FOUT + fo];
    }
    row[(size_t)b * FOUT + fo] = acc;
}

// Kernel 4: broadcast row[b] to all NR rows.  grid = (NR/ROWS_PER_BLOCK, BT).
__global__ void bcast_rows(const float* __restrict__ row, float* __restrict__ out) {
    const int rc = blockIdx.x;
    const int b  = blockIdx.y;
    const int t  = threadIdx.x;
    const float4 v = reinterpret_cast<const float4*>(row + (size_t)b * FOUT)[t];
    float4* dst = reinterpret_cast<float4*>(
        out + (size_t)b * NR * FOUT + (size_t)rc * ROWS_PER_BLOCK * FOUT) + t;
#pragma unroll 8
    for (int r = 0; r < ROWS_PER_BLOCK; ++r) {
        dst[(size_t)r * (FOUT / 4)] = v;
    }
}

extern "C" void kernel_launch(void* const* d_in, const int* in_sizes, int n_in,
                              void* d_out, int out_size, void* d_ws, size_t ws_size,
                              hipStream_t stream) {
    const float* X  = (const float*)d_in[0];
    const float* Bm = (const float*)d_in[1];
    const float* cT = (const float*)d_in[2];
    float* out = (float*)d_out;

    // workspace layout (floats): partials | mean | row
    float* part = (float*)d_ws;                       // BT*NCHUNK*FIN = 512K floats (2 MB)
    float* mean = part + (size_t)BT * NCHUNK * FIN;   // BT*FIN
    float* row  = mean + (size_t)BT * FIN;            // BT*FOUT

    colsum_partial<<<dim3(NCHUNK, BT), 256, 0, stream>>>(X, part);
    colsum_finish<<<dim3(BT), 256, 0, stream>>>(part, mean);
    matvec_row<<<dim3(FOUT / 256, BT), 256, 0, stream>>>(mean, Bm, cT, row);
    bcast_rows<<<dim3(NR / ROWS_PER_BLOCK, BT), 256, 0, stream>>>(row, out);
}

// Round 6
// 467.028 us; speedup vs baseline: 1.1095x; 1.1095x over previous
//
#include <hip/hip_runtime.h>

// Problem shape (fixed by the reference's setup_inputs)
#define BT   16
#define NR   4096
#define FIN  1024
#define FOUT 1024

#define NCHUNK 64                    // row-chunks per batch for partial colsum
#define ROWS_PER_CHUNK (NR / NCHUNK) // 64
#define ROWS_PER_BLOCK 32            // broadcast rows per block

// Kernel 1: partial column sums of X.  grid = (NCHUNK, BT), block = 256.
// 1024 blocks -> 4 blocks/CU -> 16 waves/CU; 2 independent acc chains for MLP.
__global__ void colsum_partial(const float* __restrict__ X, float* __restrict__ part) {
    const int rc = blockIdx.x;
    const int b  = blockIdx.y;
    const int t  = threadIdx.x;
    const float4* src = reinterpret_cast<const float4*>(
        X + (size_t)b * NR * FIN + (size_t)rc * ROWS_PER_CHUNK * FIN) + t;
    float4 a0 = {0.f, 0.f, 0.f, 0.f};
    float4 a1 = {0.f, 0.f, 0.f, 0.f};
#pragma unroll 4
    for (int r = 0; r < ROWS_PER_CHUNK; r += 2) {
        float4 v0 = src[(size_t)r       * (FIN / 4)];
        float4 v1 = src[(size_t)(r + 1) * (FIN / 4)];
        a0.x += v0.x; a0.y += v0.y; a0.z += v0.z; a0.w += v0.w;
        a1.x += v1.x; a1.y += v1.y; a1.z += v1.z; a1.w += v1.w;
    }
    float4 acc = {a0.x + a1.x, a0.y + a1.y, a0.z + a1.z, a0.w + a1.w};
    reinterpret_cast<float4*>(part + ((size_t)b * NCHUNK + rc) * FIN)[t] = acc;
}

// Kernel 2 (fused finish + matvec): row[b] = mean[b] @ B + cT.
// grid = (FOUT/64, BT) = 256 blocks, block = 256 = 64 fo x 4 fi-slices.
// Each block re-reduces partials for its batch (L2-resident, ~256 KB),
// then each fi-slice covers 256 fi with 2 independent accumulators.
__global__ void matvec_fused(const float* __restrict__ part, const float* __restrict__ Bm,
                             const float* __restrict__ cT, float* __restrict__ row) {
    const int foc = blockIdx.x;
    const int b   = blockIdx.y;
    const int t   = threadIdx.x;
    __shared__ float sm[FIN];
    __shared__ float red[4][64];
    // partials -> mean (in LDS)
    {
        const float4* src = reinterpret_cast<const float4*>(part + (size_t)b * NCHUNK * FIN) + t;
        float4 a = {0.f, 0.f, 0.f, 0.f};
#pragma unroll 8
        for (int c = 0; c < NCHUNK; ++c) {
            float4 v = src[(size_t)c * (FIN / 4)];
            a.x += v.x; a.y += v.y; a.z += v.z; a.w += v.w;
        }
        const float inv = 1.0f / (float)NR;
        reinterpret_cast<float4*>(sm)[t] = make_float4(a.x * inv, a.y * inv, a.z * inv, a.w * inv);
    }
    __syncthreads();
    const int fo_idx = t & 63;
    const int g      = t >> 6;            // fi-slice 0..3
    const int fo     = foc * 64 + fo_idx;
    const float* bp  = Bm + (size_t)(g * 256) * FOUT + fo;
    float f0 = 0.f, f1 = 0.f;
#pragma unroll 8
    for (int k = 0; k < 256; k += 2) {
        f0 += sm[g * 256 + k]     * bp[(size_t)k       * FOUT];
        f1 += sm[g * 256 + k + 1] * bp[(size_t)(k + 1) * FOUT];
    }
    red[g][fo_idx] = f0 + f1;
    __syncthreads();
    if (g == 0) {
        float r = red[0][fo_idx] + red[1][fo_idx] + red[2][fo_idx] + red[3][fo_idx] + cT[fo];
        row[(size_t)b * FOUT + fo] = r;
    }
}

// Kernel 3: broadcast row[b] to all NR rows.  grid = (NR/ROWS_PER_BLOCK, BT).
__global__ void bcast_rows(const float* __restrict__ row, float* __restrict__ out) {
    const int rc = blockIdx.x;
    const int b  = blockIdx.y;
    const int t  = threadIdx.x;
    const float4 v = reinterpret_cast<const float4*>(row + (size_t)b * FOUT)[t];
    float4* dst = reinterpret_cast<float4*>(
        out + (size_t)b * NR * FOUT + (size_t)rc * ROWS_PER_BLOCK * FOUT) + t;
#pragma unroll 8
    for (int r = 0; r < ROWS_PER_BLOCK; ++r) {
        dst[(size_t)r * (FOUT / 4)] = v;
    }
}

extern "C" void kernel_launch(void* const* d_in, const int* in_sizes, int n_in,
                              void* d_out, int out_size, void* d_ws, size_t ws_size,
                              hipStream_t stream) {
    const float* X  = (const float*)d_in[0];
    const float* Bm = (const float*)d_in[1];
    const float* cT = (const float*)d_in[2];
    float* out = (float*)d_out;

    // workspace layout (floats): partials | row
    float* part = (float*)d_ws;                       // BT*NCHUNK*FIN = 1M floats (4 MB)
    float* row  = part + (size_t)BT * NCHUNK * FIN;   // BT*FOUT

    colsum_partial<<<dim3(NCHUNK, BT), 256, 0, stream>>>(X, part);
    matvec_fused<<<dim3(FOUT / 64, BT), 256, 0, stream>>>(part, Bm, cT, row);
    bcast_rows<<<dim3(NR / ROWS_PER_BLOCK, BT), 256, 0, stream>>>(row, out);
}

// Round 9
// 454.257 us; speedup vs baseline: 1.1407x; 1.0281x over previous
//
#include <hip/hip_runtime.h>

// Problem shape (fixed by the reference's setup_inputs)
#define BT   16
#define NR   4096
#define FIN  1024
#define FOUT 1024

#define NCHUNK 128                       // partial-sum slices per batch
#define CS_BLOCKS 128                    // colsum blocks per batch
#define CS_STRIDE (CS_BLOCKS * 256)      // 32768 float4s; 32768 % 256 == 0 -> column fixed
#define CS_ITERS  ((NR * FIN / 4) / CS_STRIDE)   // 1M / 32768 = 32

#define BC_BLOCKS 1024
#define BC_STRIDE (BC_BLOCKS * 256)              // 262144 float4s
#define BC_ITERS  ((BT * NR * FIN / 4) / BC_STRIDE)  // 16M / 262144 = 64

// native clang vector type: accepted by __builtin_nontemporal_load/store
typedef float f32x4 __attribute__((ext_vector_type(4)));

// Kernel 1: column partial sums, flat grid-stride within each batch.
// At any instant the grid covers a contiguous 512KB span per batch -> all HBM
// channels hit uniformly (fixes the strided-base channel convoy of R5/R6).
__global__ void colsum_flat(const float* __restrict__ X, float* __restrict__ part) {
    const int b  = blockIdx.y;
    const int bt = blockIdx.x * 256 + threadIdx.x;    // 0..32767 within batch
    const f32x4* src = reinterpret_cast<const f32x4*>(X + (size_t)b * NR * FIN) + bt;
    f32x4 a0 = {0.f, 0.f, 0.f, 0.f};
    f32x4 a1 = {0.f, 0.f, 0.f, 0.f};
#pragma unroll
    for (int i = 0; i < CS_ITERS; i += 2) {
        f32x4 v0 = __builtin_nontemporal_load(&src[(size_t)i * CS_STRIDE]);
        f32x4 v1 = __builtin_nontemporal_load(&src[(size_t)(i + 1) * CS_STRIDE]);
        a0 += v0;
        a1 += v1;
    }
    f32x4 acc = a0 + a1;
    // column group c4 = bt % 256 (fixed over iters), slice k = bt / 256 in [0,128)
    reinterpret_cast<f32x4*>(part)[((size_t)b * NCHUNK + (bt >> 8)) * (FIN / 4) + (bt & 255)] = acc;
}

// Kernel 2 (fused finish + matvec): row[b] = mean[b] @ B + cT.
// grid = (FOUT/64, BT) = 256 blocks, block = 256 = 64 fo x 4 fi-slices.
__global__ void matvec_fused(const float* __restrict__ part, const float* __restrict__ Bm,
                             const float* __restrict__ cT, float* __restrict__ row) {
    const int foc = blockIdx.x;
    const int b   = blockIdx.y;
    const int t   = threadIdx.x;
    __shared__ float sm[FIN];
    __shared__ float red[4][64];
    // partials -> mean (in LDS); partials are L2-resident (8MB, read 16x)
    {
        const f32x4* src = reinterpret_cast<const f32x4*>(part) + (size_t)b * NCHUNK * (FIN / 4) + t;
        f32x4 a = {0.f, 0.f, 0.f, 0.f};
#pragma unroll 8
        for (int c = 0; c < NCHUNK; ++c) {
            a += src[(size_t)c * (FIN / 4)];
        }
        const float inv = 1.0f / (float)NR;
        a *= inv;
        reinterpret_cast<f32x4*>(sm)[t] = a;
    }
    __syncthreads();
    const int fo_idx = t & 63;
    const int g      = t >> 6;            // fi-slice 0..3
    const int fo     = foc * 64 + fo_idx;
    const float* bp  = Bm + (size_t)(g * 256) * FOUT + fo;
    float f0 = 0.f, f1 = 0.f;
#pragma unroll 8
    for (int k = 0; k < 256; k += 2) {
        f0 += sm[g * 256 + k]     * bp[(size_t)k       * FOUT];
        f1 += sm[g * 256 + k + 1] * bp[(size_t)(k + 1) * FOUT];
    }
    red[g][fo_idx] = f0 + f1;
    __syncthreads();
    if (g == 0) {
        float r = red[0][fo_idx] + red[1][fo_idx] + red[2][fo_idx] + red[3][fo_idx] + cT[fo];
        row[(size_t)b * FOUT + fo] = r;
    }
}

// Kernel 3: broadcast, flat grid-stride over the whole 256MB output.
// batch index per iter is i>>2 (compile-time after unroll); row values
// preloaded into 16 f32x4 registers; nontemporal stores.
__global__ void bcast_flat(const float* __restrict__ row, float* __restrict__ out) {
    const int tid = blockIdx.x * 256 + threadIdx.x;   // 0..BC_STRIDE-1
    const int c4  = tid & 255;                        // fixed column group
    f32x4 v[BT];
#pragma unroll
    for (int b = 0; b < BT; ++b)
        v[b] = reinterpret_cast<const f32x4*>(row + (size_t)b * FOUT)[c4];
    f32x4* dst = reinterpret_cast<f32x4*>(out) + tid;
#pragma unroll
    for (int i = 0; i < BC_ITERS; ++i) {
        __builtin_nontemporal_store(v[i >> 2], &dst[(size_t)i * BC_STRIDE]);
    }
}

extern "C" void kernel_launch(void* const* d_in, const int* in_sizes, int n_in,
                              void* d_out, int out_size, void* d_ws, size_t ws_size,
                              hipStream_t stream) {
    const float* X  = (const float*)d_in[0];
    const float* Bm = (const float*)d_in[1];
    const float* cT = (const float*)d_in[2];
    float* out = (float*)d_out;

    // workspace layout (floats): partials (8MB) | row
    float* part = (float*)d_ws;                       // BT*NCHUNK*FIN = 2M floats
    float* row  = part + (size_t)BT * NCHUNK * FIN;   // BT*FOUT

    colsum_flat<<<dim3(CS_BLOCKS, BT), 256, 0, stream>>>(X, part);
    matvec_fused<<<dim3(FOUT / 64, BT), 256, 0, stream>>>(part, Bm, cT, row);
    bcast_flat<<<dim3(BC_BLOCKS), 256, 0, stream>>>(row, out);
}